// Round 2
// baseline (577.789 us; speedup 1.0000x reference)
//
#include <hip/hip_runtime.h>

#define HW 64
#define STR 68           // LDS row stride: 4*row mod 32 gives distinct bank shifts per wave row
#define ROWS 36          // 32 owned + 2 v-halo + 2 X-halo rows
#define BUF (ROWS*STR)   // 2448 floats = 9792 B per buffer
#define LH 150
#define LQ 10

// ws layout (bytes): [0,76) weff | [256,16640) flags (256 x 64B) | [16640,164096) halo slots (512 x 288B)
#define WS_FLAG_OFF 256
#define WS_HALO_OFF 16640
#define SLOT_F 72        // floats per halo slot (288 B)

__global__ void vin_prep(const float* __restrict__ h_w,
                         const float* __restrict__ h_b,
                         const float* __restrict__ r_w,
                         float* __restrict__ weff) {
    int t = threadIdx.x;
    if (t < 18) {
        float s = 0.f;
        for (int l = 0; l < LH; ++l) s += r_w[l] * h_w[l*18 + t];
        weff[t] = s;
    } else if (t == 18) {
        float s = 0.f;
        for (int l = 0; l < LH; ++l) s += r_w[l] * h_b[l];
        weff[18] = s;
    }
}

// Load 6 cols [x0-1 .. x0+4] in padded coords: rowp points at row*stride + x0 (16B aligned).
__device__ __forceinline__ void load_row6(const float* rowp, float* dst) {
    float2 L = *(const float2*)(rowp + 2);
    float4 M = *(const float4*)(rowp + 4);
    float  R = rowp[8];
    dst[0] = L.y; dst[1] = M.x; dst[2] = M.y; dst[3] = M.z; dst[4] = M.w; dst[5] = R;
}

// 256 blocks: (image b = bid>>1, half s = bid&1). Each block owns 32 rows; halves exchange
// one boundary row per step via global parity slots + device-scope flags. Only the 16
// boundary-row threads spin (acquire) and read the halo straight into window registers.
__global__ __launch_bounds__(512, 2)
void vin_main(const float* __restrict__ X,
              const float* __restrict__ q_w,
              const float* __restrict__ wgt,
              const int* __restrict__ kptr,
              float* __restrict__ ws,
              float* __restrict__ out) {
    __shared__ float sA[BUF];   // X ch0 -> v ping
    __shared__ float sB[BUF];   // X ch1 -> v pong
    __shared__ float sC[BUF];   // r
    const int bid = blockIdx.x;
    const int b = bid >> 1, s = bid & 1;
    const int tid = threadIdx.x;
    const int GB = s*32 - 2;    // global image row of LDS row 0

    unsigned* myFlag = (unsigned*)((char*)ws + WS_FLAG_OFF) + bid*16;
    unsigned* paFlag = (unsigned*)((char*)ws + WS_FLAG_OFF) + (bid^1)*16;
    float* haloBase  = (float*)((char*)ws + WS_HALO_OFF);
    float* mySlot    = haloBase + (size_t)bid*2*SLOT_F;
    const float* paSlot = haloBase + (size_t)(bid^1)*2*SLOT_F;
    const float* weff = ws;

    for (int i = tid; i < BUF; i += 512) { sA[i]=0.f; sB[i]=0.f; sC[i]=0.f; }
    __syncthreads();

    // ---- stage X rows GB..GB+35 (zeros outside image) ----
    const float* Xb = X + (size_t)b * 2 * HW * HW;
    for (int i = tid; i < 2*ROWS*16; i += 512) {
        int ch = (i >= ROWS*16) ? 1 : 0;
        int j = i - ch*ROWS*16;
        int row = j >> 4, c = j & 15;
        int grow = GB + row;
        if (grow >= 0 && grow < HW) {
            float4 v = *(const float4*)(Xb + ((size_t)ch*HW + grow)*HW + c*4);
            float* dstb = ch ? sB : sA;
            *(float4*)(dstb + row*STR + 4 + c*4) = v;
        }
    }
    __syncthreads();

    // ---- r = fused h->r conv on LDS rows 1..34 (zero where outside image) ----
    float wE[19];
    #pragma unroll
    for (int i = 0; i < 19; ++i) wE[i] = weff[i];
    for (int i = tid; i < 34*16; i += 512) {
        int lr = 1 + (i >> 4), c = i & 15;
        int grow = GB + lr;
        float4 v4 = {0.f, 0.f, 0.f, 0.f};
        if (grow >= 0 && grow < HW) {
            float w0[3][6], w1[3][6];
            #pragma unroll
            for (int d = 0; d < 3; ++d) {
                load_row6(sA + (lr-1+d)*STR + c*4, w0[d]);
                load_row6(sB + (lr-1+d)*STR + c*4, w1[d]);
            }
            float vv[4];
            #pragma unroll
            for (int x = 0; x < 4; ++x) {
                float acc = wE[18];
                #pragma unroll
                for (int dy = 0; dy < 3; ++dy)
                    #pragma unroll
                    for (int dx = 0; dx < 3; ++dx) {
                        acc += w0[dy][x+dx] * wE[dy*3+dx];
                        acc += w1[dy][x+dx] * wE[9 + dy*3+dx];
                    }
                vv[x] = acc;
            }
            v4.x = vv[0]; v4.y = vv[1]; v4.z = vv[2]; v4.w = vv[3];
        }
        *(float4*)(sC + lr*STR + 4 + c*4) = v4;
    }
    __syncthreads();

    // ---- per-thread ownership: 1 row x 4 cols ----
    const int r  = tid >> 4, c = tid & 15, x0 = c*4;
    const int L  = r + 2;                         // LDS row of owned row
    const bool isBnd = s ? (r == 0) : (r == 31);  // row adjacent to the split boundary
    const int haloWinRow = s ? 0 : 2;             // which window row comes from partner

    // ---- qr[a] = conv3x3(r, q_w[a]) on owned px; v0 = max_a qr ----
    float win[3][6];
    #pragma unroll
    for (int d = 0; d < 3; ++d) load_row6(sC + (L-1+d)*STR + x0, win[d]);
    float qr[LQ][4], vcur[4];
    #pragma unroll
    for (int a = 0; a < LQ; ++a) {
        #pragma unroll
        for (int x = 0; x < 4; ++x) {
            float acc = 0.f;
            #pragma unroll
            for (int dy = 0; dy < 3; ++dy)
                #pragma unroll
                for (int dx = 0; dx < 3; ++dx)
                    acc += win[dy][x+dx] * q_w[a*9 + dy*3 + dx];
            qr[a][x] = acc;
            vcur[x] = a ? fmaxf(vcur[x], acc) : acc;
        }
    }
    // step 0: v0 -> sA owned rows; boundary row -> slot[0]; flag = 1
    {
        float4 v4 = {vcur[0], vcur[1], vcur[2], vcur[3]};
        *(float4*)(sA + L*STR + 4 + x0) = v4;
        if (isBnd) {
            *(float4*)(mySlot + 0*SLOT_F + 4 + x0) = v4;
            __threadfence();
        }
    }
    __syncthreads();
    if (tid == 0) __hip_atomic_store(myFlag, 1u, __ATOMIC_RELEASE, __HIP_MEMORY_SCOPE_AGENT);

    // ---- value iteration: v <- max_a (qr[a] + conv3x3(v, w[a])) ----
    float wv[LQ][9];
    #pragma unroll
    for (int a = 0; a < LQ; ++a)
        #pragma unroll
        for (int i = 0; i < 9; ++i) wv[a][i] = wgt[a*9 + i];

    const int km1 = kptr[0] - 1;
    float* cur = sA;
    float* nxt = sB;
    for (int t = 1; t <= km1; ++t) {
        float w2[3][6];
        #pragma unroll
        for (int d = 0; d < 3; ++d) load_row6(cur + (L-1+d)*STR + x0, w2[d]);
        if (isBnd) {
            while (__hip_atomic_load(paFlag, __ATOMIC_ACQUIRE, __HIP_MEMORY_SCOPE_AGENT) < (unsigned)t)
                __builtin_amdgcn_s_sleep(1);
            load_row6(paSlot + ((t-1)&1)*SLOT_F + x0, w2[haloWinRow]);
        }
        float vn[4];
        #pragma unroll
        for (int a = 0; a < LQ; ++a) {
            #pragma unroll
            for (int x = 0; x < 4; ++x) {
                float acc = qr[a][x];
                #pragma unroll
                for (int dy = 0; dy < 3; ++dy)
                    #pragma unroll
                    for (int dx = 0; dx < 3; ++dx)
                        acc += w2[dy][x+dx] * wv[a][dy*3 + dx];
                vn[x] = a ? fmaxf(vn[x], acc) : acc;
            }
        }
        float4 v4 = {vn[0], vn[1], vn[2], vn[3]};
        *(float4*)(nxt + L*STR + 4 + x0) = v4;
        if (isBnd) {
            *(float4*)(mySlot + (t&1)*SLOT_F + 4 + x0) = v4;
            __threadfence();
        }
        __syncthreads();
        if (tid == 0) __hip_atomic_store(myFlag, (unsigned)(t+1), __ATOMIC_RELEASE, __HIP_MEMORY_SCOPE_AGENT);
        float* tmp = cur; cur = nxt; nxt = tmp;
    }

    // ---- write out owned rows ----
    const int gr = s*32 + r;
    float4 o = *(const float4*)(cur + L*STR + 4 + x0);
    *(float4*)(out + (size_t)b*HW*HW + (size_t)gr*HW + x0) = o;
}

extern "C" void kernel_launch(void* const* d_in, const int* in_sizes, int n_in,
                              void* d_out, int out_size, void* d_ws, size_t ws_size,
                              hipStream_t stream) {
    const float* X   = (const float*)d_in[0];
    const float* h_w = (const float*)d_in[1];
    const float* h_b = (const float*)d_in[2];
    const float* r_w = (const float*)d_in[3];
    const float* q_w = (const float*)d_in[4];
    const float* w   = (const float*)d_in[5];
    const int*   k   = (const int*)d_in[6];
    float* out = (float*)d_out;
    float* ws  = (float*)d_ws;

    vin_prep<<<1, 64, 0, stream>>>(h_w, h_b, r_w, ws);
    // zero flags + halo slots (re-poisoned to 0xAA before every timed launch)
    hipMemsetAsync((char*)d_ws + WS_FLAG_OFF, 0, 164096 - WS_FLAG_OFF, stream);

    void* args[] = { (void*)&X, (void*)&q_w, (void*)&w, (void*)&k, (void*)&ws, (void*)&out };
    hipLaunchCooperativeKernel(reinterpret_cast<void*>(vin_main),
                               dim3(256), dim3(512), args, 0, stream);
}

// Round 4
// 186.416 us; speedup vs baseline: 3.0995x; 3.0995x over previous
//
#include <hip/hip_runtime.h>

typedef float f2 __attribute__((ext_vector_type(2)));

#define HW 64
#define SF 68            // f32 LDS row stride (words); 16B-aligned rows
#define RB (66*SF)       // 4488 floats per buffer (64 rows + 2 halo)
#define LH 150
#define LQ 10

// weff[0..17] = sum_l r_w[l]*h_w[l][c][ky][kx], weff[18] = sum_l r_w[l]*h_b[l]
__global__ void vin_prep(const float* __restrict__ h_w,
                         const float* __restrict__ h_b,
                         const float* __restrict__ r_w,
                         float* __restrict__ weff) {
    int t = threadIdx.x;
    if (t < 18) {
        float s = 0.f;
        for (int l = 0; l < LH; ++l) s += r_w[l] * h_w[l*18 + t];
        weff[t] = s;
    } else if (t == 18) {
        float s = 0.f;
        for (int l = 0; l < LH; ++l) s += r_w[l] * h_b[l];
        weff[18] = s;
    }
}

// Load 6 f32 cols [x0-1 .. x0+4] in padded coords (rowp = base + row*SF + x0).
__device__ __forceinline__ void load_row6(const float* rowp, float* dst) {
    float2 L = *(const float2*)(rowp + 2);
    float4 M = *(const float4*)(rowp + 4);
    float  R = rowp[8];
    dst[0] = L.y; dst[1] = M.x; dst[2] = M.y; dst[3] = M.z; dst[4] = M.w; dst[5] = R;
}

// One block per image, 1024 threads, each owns 1 row x 4 cols (two f32 pairs).
// All fp32. Value-iteration inner loop uses packed v_pk_fma_f32 / v_pk_max_f32
// via float2 ext-vector elementwise builtins. v ping-pongs in zero-haloed LDS.
__global__ __launch_bounds__(1024)
void vin_main(const float* __restrict__ X,
              const float* __restrict__ q_w,
              const float* __restrict__ wgt,
              const int* __restrict__ kptr,
              const float* __restrict__ ws,
              float* __restrict__ out) {
    __shared__ float smem[3*RB];           // 53856 B
    float* sA = smem;                      // X ch0 -> v ping
    float* sB = smem + RB;                 // X ch1 -> v pong
    float* sC = smem + 2*RB;               // r

    const int b = blockIdx.x, tid = threadIdx.x;
    const int r = tid >> 4, c = tid & 15, x0 = c * 4;
    const int L = r + 1;                   // LDS row of owned image row

    for (int i = tid; i < 3*RB; i += 1024) smem[i] = 0.f;
    __syncthreads();

    // ---- stage X (both channels), image rows -1..64 -> LDS rows 0..65 ----
    const float* Xb = X + (size_t)b * 2 * HW * HW;
    for (int i = tid; i < 2*66*16; i += 1024) {
        int ch = (i >= 66*16) ? 1 : 0;
        int j = i - ch*66*16;
        int row = j >> 4, cc = j & 15, g = row - 1;
        if ((unsigned)g < (unsigned)HW) {
            float4 v = *(const float4*)(Xb + ((size_t)ch*HW + g)*HW + cc*4);
            *(float4*)(smem + ch*RB + row*SF + 4 + cc*4) = v;
        }
    }
    __syncthreads();

    // ---- r = conv3x3(X, weff) + beff ----
    float wE[19];
    #pragma unroll
    for (int i = 0; i < 19; ++i) wE[i] = ws[i];
    {
        float w0[3][6], w1[3][6];
        #pragma unroll
        for (int d = 0; d < 3; ++d) {
            load_row6(sA + (L-1+d)*SF + x0, w0[d]);
            load_row6(sB + (L-1+d)*SF + x0, w1[d]);
        }
        float rv[4];
        #pragma unroll
        for (int x = 0; x < 4; ++x) {
            float acc = wE[18];
            #pragma unroll
            for (int dy = 0; dy < 3; ++dy)
                #pragma unroll
                for (int dx = 0; dx < 3; ++dx) {
                    acc += w0[dy][x+dx] * wE[dy*3+dx];
                    acc += w1[dy][x+dx] * wE[9 + dy*3+dx];
                }
            rv[x] = acc;
        }
        float4 o = {rv[0], rv[1], rv[2], rv[3]};
        *(float4*)(sC + L*SF + 4 + x0) = o;
    }
    __syncthreads();

    // ---- qr[a] = conv3x3(r, q_w[a]) in regs (as f32 pairs); v0 = max_a qr ----
    float winr[3][6];
    #pragma unroll
    for (int d = 0; d < 3; ++d) load_row6(sC + (L-1+d)*SF + x0, winr[d]);
    f2 qr[LQ][2];
    float vcur[4];
    #pragma unroll
    for (int a = 0; a < LQ; ++a) {
        float acc[4];
        #pragma unroll
        for (int x = 0; x < 4; ++x) {
            float s = 0.f;
            #pragma unroll
            for (int dy = 0; dy < 3; ++dy)
                #pragma unroll
                for (int dx = 0; dx < 3; ++dx)
                    s += winr[dy][x+dx] * q_w[a*9 + dy*3 + dx];
            acc[x] = s;
            vcur[x] = a ? fmaxf(vcur[x], s) : s;
        }
        qr[a][0] = (f2){acc[0], acc[1]};
        qr[a][1] = (f2){acc[2], acc[3]};
    }
    __syncthreads();       // sA's X data fully consumed (r done earlier); safe to overwrite
    {
        float4 o = {vcur[0], vcur[1], vcur[2], vcur[3]};
        *(float4*)(sA + L*SF + 4 + x0) = o;
    }
    __syncthreads();

    // ---- value iteration: v <- max_a (qr[a] + conv3x3(v, w[a])), packed f32 ----
    float wv[LQ][9];
    #pragma unroll
    for (int a = 0; a < LQ; ++a)
        #pragma unroll
        for (int i = 0; i < 9; ++i) wv[a][i] = wgt[a*9 + i];

    const int km1 = kptr[0] - 1;
    float* cur = sA;
    float* nxt = sB;
    for (int t = 0; t < km1; ++t) {
        // window rows: 6 cols x0-1..x0+4 -> 5 shifted f32 pairs per row
        f2 p[3][5];
        #pragma unroll
        for (int d = 0; d < 3; ++d) {
            const float* rp = cur + (L-1+d)*SF;
            float lf  = rp[3 + x0];                       // col x0-1
            float4 M  = *(const float4*)(rp + 4 + x0);    // cols x0..x0+3
            float rt  = rp[8 + x0];                       // col x0+4
            p[d][0] = (f2){lf,  M.x};
            p[d][1] = (f2){M.x, M.y};
            p[d][2] = (f2){M.y, M.z};
            p[d][3] = (f2){M.z, M.w};
            p[d][4] = (f2){M.w, rt};
        }
        f2 vA, vB;
        #pragma unroll
        for (int a = 0; a < LQ; ++a) {
            f2 aA = qr[a][0], aB = qr[a][1];
            #pragma unroll
            for (int d = 0; d < 3; ++d) {
                float w0 = wv[a][3*d], w1 = wv[a][3*d+1], w2 = wv[a][3*d+2];
                aA = __builtin_elementwise_fma(p[d][0], (f2){w0, w0}, aA);
                aA = __builtin_elementwise_fma(p[d][1], (f2){w1, w1}, aA);
                aA = __builtin_elementwise_fma(p[d][2], (f2){w2, w2}, aA);
                aB = __builtin_elementwise_fma(p[d][2], (f2){w0, w0}, aB);
                aB = __builtin_elementwise_fma(p[d][3], (f2){w1, w1}, aB);
                aB = __builtin_elementwise_fma(p[d][4], (f2){w2, w2}, aB);
            }
            if (a == 0) { vA = aA; vB = aB; }
            else { vA = __builtin_elementwise_max(vA, aA);
                   vB = __builtin_elementwise_max(vB, aB); }
        }
        float4 o = {vA.x, vA.y, vB.x, vB.y};
        *(float4*)(nxt + L*SF + 4 + x0) = o;
        __syncthreads();
        float* tmp = cur; cur = nxt; nxt = tmp;
    }

    // ---- write out owned row (coalesced float4) ----
    float4 o = *(const float4*)(cur + L*SF + 4 + x0);
    *(float4*)(out + (size_t)b*HW*HW + (size_t)r*HW + x0) = o;
}

extern "C" void kernel_launch(void* const* d_in, const int* in_sizes, int n_in,
                              void* d_out, int out_size, void* d_ws, size_t ws_size,
                              hipStream_t stream) {
    const float* X   = (const float*)d_in[0];
    const float* h_w = (const float*)d_in[1];
    const float* h_b = (const float*)d_in[2];
    const float* r_w = (const float*)d_in[3];
    const float* q_w = (const float*)d_in[4];
    const float* w   = (const float*)d_in[5];
    const int*   k   = (const int*)d_in[6];
    float* out = (float*)d_out;
    float* ws  = (float*)d_ws;   // 19 floats

    vin_prep<<<1, 64, 0, stream>>>(h_w, h_b, r_w, ws);
    vin_main<<<128, 1024, 0, stream>>>(X, q_w, w, k, ws, out);
}

// Round 6
// 181.071 us; speedup vs baseline: 3.1909x; 1.0295x over previous
//
#include <hip/hip_runtime.h>

typedef float f2 __attribute__((ext_vector_type(2)));

#define HW 64
#define SF 68            // f32 LDS row stride (words); 16B-aligned rows
#define RB (66*SF)       // 4488 floats per buffer (64 rows + 2 halo)
#define LH 150
#define LQ 10

// weff[0..17] = sum_l r_w[l]*h_w[l][c][ky][kx], weff[18] = sum_l r_w[l]*h_b[l]
__global__ void vin_prep(const float* __restrict__ h_w,
                         const float* __restrict__ h_b,
                         const float* __restrict__ r_w,
                         float* __restrict__ weff) {
    int t = threadIdx.x;
    if (t < 18) {
        float s = 0.f;
        for (int l = 0; l < LH; ++l) s += r_w[l] * h_w[l*18 + t];
        weff[t] = s;
    } else if (t == 18) {
        float s = 0.f;
        for (int l = 0; l < LH; ++l) s += r_w[l] * h_b[l];
        weff[18] = s;
    }
}

// Load 6 f32 cols [x0-1 .. x0+4]; rowp = base + row*SF + x0 (16B aligned).
// All-b128 reads: edge cols come from the adjacent aligned float4s (pads are zero,
// so image-border halos are correct SAME-padding zeros for free).
__device__ __forceinline__ void load6(const float* rowp, float* dst) {
    float4 E = *(const float4*)(rowp);       // cols x0-4..x0-1 (use .w)
    float4 M = *(const float4*)(rowp + 4);   // cols x0..x0+3
    float4 F = *(const float4*)(rowp + 8);   // cols x0+4..x0+7 (use .x)
    dst[0] = E.w; dst[1] = M.x; dst[2] = M.y; dst[3] = M.z; dst[4] = M.w; dst[5] = F.x;
}

// One block per image, 1024 threads, each owns 1 row x 4 cols (two f32 pairs).
// All fp32. Inner loop uses packed f2 fma/max. v ping-pongs in zero-haloed LDS.
__global__ __launch_bounds__(1024)
void vin_main(const float* __restrict__ X,
              const float* __restrict__ q_w,
              const float* __restrict__ wgt,
              const int* __restrict__ kptr,
              const float* __restrict__ ws,
              float* __restrict__ out) {
    __shared__ float smem[3*RB + 4];       // +4: zeroed tail pad for row-65 edge reads
    float* sA = smem;                      // X ch0 -> v ping
    float* sB = smem + RB;                 // X ch1 -> v pong
    float* sC = smem + 2*RB;               // r

    const int b = blockIdx.x, tid = threadIdx.x;
    const int r = tid >> 4, c = tid & 15, x0 = c * 4;
    const int L = r + 1;                   // LDS row of owned image row

    for (int i = tid; i < 3*RB + 4; i += 1024) smem[i] = 0.f;
    __syncthreads();

    // ---- stage X (both channels), image rows -1..64 -> LDS rows 0..65 ----
    const float* Xb = X + (size_t)b * 2 * HW * HW;
    for (int i = tid; i < 2*66*16; i += 1024) {
        int ch = (i >= 66*16) ? 1 : 0;
        int j = i - ch*66*16;
        int row = j >> 4, cc = j & 15, g = row - 1;
        if ((unsigned)g < (unsigned)HW) {
            float4 v = *(const float4*)(Xb + ((size_t)ch*HW + g)*HW + cc*4);
            *(float4*)(smem + ch*RB + row*SF + 4 + cc*4) = v;
        }
    }
    __syncthreads();

    // ---- r = conv3x3(X, weff) + beff ----
    float wE[19];
    #pragma unroll
    for (int i = 0; i < 19; ++i) wE[i] = ws[i];
    {
        float w0[3][6], w1[3][6];
        #pragma unroll
        for (int d = 0; d < 3; ++d) {
            load6(sA + (L-1+d)*SF + x0, w0[d]);
            load6(sB + (L-1+d)*SF + x0, w1[d]);
        }
        float rv[4];
        #pragma unroll
        for (int x = 0; x < 4; ++x) {
            float acc = wE[18];
            #pragma unroll
            for (int dy = 0; dy < 3; ++dy)
                #pragma unroll
                for (int dx = 0; dx < 3; ++dx) {
                    acc += w0[dy][x+dx] * wE[dy*3+dx];
                    acc += w1[dy][x+dx] * wE[9 + dy*3+dx];
                }
            rv[x] = acc;
        }
        float4 o = {rv[0], rv[1], rv[2], rv[3]};
        *(float4*)(sC + L*SF + 4 + x0) = o;
    }
    __syncthreads();

    // ---- qr[a] = conv3x3(r, q_w[a]) in regs (as f32 pairs); v0 = max_a qr ----
    float winr[3][6];
    #pragma unroll
    for (int d = 0; d < 3; ++d) load6(sC + (L-1+d)*SF + x0, winr[d]);
    f2 qr[LQ][2];
    float vcur[4];
    #pragma unroll
    for (int a = 0; a < LQ; ++a) {
        float acc[4];
        #pragma unroll
        for (int x = 0; x < 4; ++x) {
            float s = 0.f;
            #pragma unroll
            for (int dy = 0; dy < 3; ++dy)
                #pragma unroll
                for (int dx = 0; dx < 3; ++dx)
                    s += winr[dy][x+dx] * q_w[a*9 + dy*3 + dx];
            acc[x] = s;
            vcur[x] = a ? fmaxf(vcur[x], s) : s;
        }
        qr[a][0] = (f2){acc[0], acc[1]};
        qr[a][1] = (f2){acc[2], acc[3]};
    }
    __syncthreads();       // sA's X data fully consumed; safe to overwrite
    {
        float4 o = {vcur[0], vcur[1], vcur[2], vcur[3]};
        *(float4*)(sA + L*SF + 4 + x0) = o;
    }
    __syncthreads();

    // ---- value iteration: v <- max_a (qr[a] + conv3x3(v, w[a])), packed f32 ----
    float wv[LQ][9];
    #pragma unroll
    for (int a = 0; a < LQ; ++a)
        #pragma unroll
        for (int i = 0; i < 9; ++i) wv[a][i] = wgt[a*9 + i];

    const int km1 = kptr[0] - 1;
    float* cur = sA;
    float* nxt = sB;
    for (int t = 0; t < km1; ++t) {
        // window rows: 6 cols x0-1..x0+4 -> 5 shifted f32 pairs per row (all-b128 loads)
        f2 p[3][5];
        #pragma unroll
        for (int d = 0; d < 3; ++d) {
            const float* rp = cur + (L-1+d)*SF + x0;
            float4 E = *(const float4*)(rp);      // .w = col x0-1
            float4 M = *(const float4*)(rp + 4);  // cols x0..x0+3
            float4 F = *(const float4*)(rp + 8);  // .x = col x0+4
            p[d][0] = (f2){E.w, M.x};
            p[d][1] = (f2){M.x, M.y};
            p[d][2] = (f2){M.y, M.z};
            p[d][3] = (f2){M.z, M.w};
            p[d][4] = (f2){M.w, F.x};
        }
        f2 vA, vB;
        #pragma unroll
        for (int a = 0; a < LQ; ++a) {
            f2 aA = qr[a][0], aB = qr[a][1];
            #pragma unroll
            for (int d = 0; d < 3; ++d) {
                float w0 = wv[a][3*d], w1 = wv[a][3*d+1], w2 = wv[a][3*d+2];
                aA = __builtin_elementwise_fma(p[d][0], (f2){w0, w0}, aA);
                aA = __builtin_elementwise_fma(p[d][1], (f2){w1, w1}, aA);
                aA = __builtin_elementwise_fma(p[d][2], (f2){w2, w2}, aA);
                aB = __builtin_elementwise_fma(p[d][2], (f2){w0, w0}, aB);
                aB = __builtin_elementwise_fma(p[d][3], (f2){w1, w1}, aB);
                aB = __builtin_elementwise_fma(p[d][4], (f2){w2, w2}, aB);
            }
            if (a == 0) { vA = aA; vB = aB; }
            else { vA = __builtin_elementwise_max(vA, aA);
                   vB = __builtin_elementwise_max(vB, aB); }
        }
        float4 o = {vA.x, vA.y, vB.x, vB.y};
        *(float4*)(nxt + L*SF + 4 + x0) = o;
        __syncthreads();
        float* tmp = cur; cur = nxt; nxt = tmp;
    }

    // ---- write out owned row (coalesced float4) ----
    float4 o = *(const float4*)(cur + L*SF + 4 + x0);
    *(float4*)(out + (size_t)b*HW*HW + (size_t)r*HW + x0) = o;
}

extern "C" void kernel_launch(void* const* d_in, const int* in_sizes, int n_in,
                              void* d_out, int out_size, void* d_ws, size_t ws_size,
                              hipStream_t stream) {
    const float* X   = (const float*)d_in[0];
    const float* h_w = (const float*)d_in[1];
    const float* h_b = (const float*)d_in[2];
    const float* r_w = (const float*)d_in[3];
    const float* q_w = (const float*)d_in[4];
    const float* w   = (const float*)d_in[5];
    const int*   k   = (const int*)d_in[6];
    float* out = (float*)d_out;
    float* ws  = (float*)d_ws;   // 19 floats

    vin_prep<<<1, 64, 0, stream>>>(h_w, h_b, r_w, ws);
    vin_main<<<128, 1024, 0, stream>>>(X, q_w, w, k, ws, out);
}

// Round 7
// 176.803 us; speedup vs baseline: 3.2680x; 1.0241x over previous
//
#include <hip/hip_runtime.h>

typedef float f2 __attribute__((ext_vector_type(2)));

#define HW 64
#define SF 68            // f32 LDS row stride (words); right halo of each row = next row's zero pad
#define RB (66*SF)       // 4488 floats per buffer (64 rows + 2 halo rows)
#define LH 150
#define LQ 10

// weff[0..17] = sum_l r_w[l]*h_w[l][c][ky][kx], weff[18] = sum_l r_w[l]*h_b[l]
__global__ void vin_prep(const float* __restrict__ h_w,
                         const float* __restrict__ h_b,
                         const float* __restrict__ r_w,
                         float* __restrict__ weff) {
    int t = threadIdx.x;
    if (t < 18) {
        float s = 0.f;
        for (int l = 0; l < LH; ++l) s += r_w[l] * h_w[l*18 + t];
        weff[t] = s;
    } else if (t == 18) {
        float s = 0.f;
        for (int l = 0; l < LH; ++l) s += r_w[l] * h_b[l];
        weff[18] = s;
    }
}

// Load 10 f32 cols [x0-1 .. x0+8]; rp = base + row*SF + 4 + x0 (16B aligned, points at col x0).
// All-b128: edge cols from adjacent aligned float4s; pads are zero => SAME padding for free.
__device__ __forceinline__ void load10(const float* rp, float* w10) {
    float4 E  = *(const float4*)(rp - 4);   // .w = col x0-1
    float4 M0 = *(const float4*)(rp);       // cols x0..x0+3
    float4 M1 = *(const float4*)(rp + 4);   // cols x0+4..x0+7
    float4 F  = *(const float4*)(rp + 8);   // .x = col x0+8
    w10[0]=E.w;  w10[1]=M0.x; w10[2]=M0.y; w10[3]=M0.z; w10[4]=M0.w;
    w10[5]=M1.x; w10[6]=M1.y; w10[7]=M1.z; w10[8]=M1.w; w10[9]=F.x;
}

// One block per image, 512 threads, each owns 1 row x 8 cols.
// __launch_bounds__(512,2): 2 waves/SIMD -> 256-VGPR budget so qr[80]+wv[90] stay
// in true VGPRs (R6's 1024-thread config capped at 128 VGPRs -> AGPR churn).
__global__ __launch_bounds__(512, 2)
void vin_main(const float* __restrict__ X,
              const float* __restrict__ q_w,
              const float* __restrict__ wgt,
              const int* __restrict__ kptr,
              const float* __restrict__ ws,
              float* __restrict__ out) {
    __shared__ float smem[3*RB + 4];       // +4: zeroed tail pad for row-65 edge reads of sC
    float* sA = smem;                      // X ch0 -> v ping
    float* sB = smem + RB;                 // X ch1 -> v pong
    float* sC = smem + 2*RB;               // r

    const int b = blockIdx.x, tid = threadIdx.x;
    const int r = tid >> 3, c = tid & 7, x0 = c * 8;
    const int L = r + 1;                   // LDS row of owned image row

    for (int i = tid; i < 3*RB + 4; i += 512) smem[i] = 0.f;
    __syncthreads();

    // ---- stage X (both channels), image rows 0..63 -> LDS rows 1..64 ----
    const float* Xb = X + (size_t)b * 2 * HW * HW;
    for (int i = tid; i < 2*64*16; i += 512) {
        int ch = i >> 10;
        int j = i & 1023;
        int row = j >> 4, cc = j & 15;
        float4 v = *(const float4*)(Xb + ((size_t)ch*HW + row)*HW + cc*4);
        *(float4*)(smem + ch*RB + (row+1)*SF + 4 + cc*4) = v;
    }
    __syncthreads();

    // ---- r = conv3x3(X, weff) + beff on owned 8 px ----
    float wE[19];
    #pragma unroll
    for (int i = 0; i < 19; ++i) wE[i] = ws[i];
    {
        float rr[8];
        #pragma unroll
        for (int px = 0; px < 8; ++px) rr[px] = wE[18];
        #pragma unroll
        for (int ch = 0; ch < 2; ++ch) {
            #pragma unroll
            for (int d = 0; d < 3; ++d) {
                float w10[10];
                load10(smem + ch*RB + (L-1+d)*SF + 4 + x0, w10);
                #pragma unroll
                for (int px = 0; px < 8; ++px)
                    #pragma unroll
                    for (int j = 0; j < 3; ++j)
                        rr[px] = fmaf(w10[px+j], wE[ch*9 + d*3 + j], rr[px]);
            }
        }
        float4 o0 = {rr[0], rr[1], rr[2], rr[3]};
        float4 o1 = {rr[4], rr[5], rr[6], rr[7]};
        *(float4*)(sC + L*SF + 4 + x0) = o0;
        *(float4*)(sC + L*SF + 8 + x0) = o1;
    }
    __syncthreads();

    // ---- qr[a] = conv3x3(r, q_w[a]) (f2 pairs in regs); v0 = max_a qr ----
    f2 qr[LQ][4];
    float vcur[8];
    {
        float w10[3][10];
        #pragma unroll
        for (int d = 0; d < 3; ++d) load10(sC + (L-1+d)*SF + 4 + x0, w10[d]);
        #pragma unroll
        for (int a = 0; a < LQ; ++a) {
            float qa[9];
            #pragma unroll
            for (int i = 0; i < 9; ++i) qa[i] = q_w[a*9 + i];
            float acc[8];
            #pragma unroll
            for (int px = 0; px < 8; ++px) {
                float s = 0.f;
                #pragma unroll
                for (int d = 0; d < 3; ++d)
                    #pragma unroll
                    for (int j = 0; j < 3; ++j)
                        s = fmaf(w10[d][px+j], qa[d*3+j], s);
                acc[px] = s;
                vcur[px] = a ? fmaxf(vcur[px], s) : s;
            }
            #pragma unroll
            for (int j = 0; j < 4; ++j) qr[a][j] = (f2){acc[2*j], acc[2*j+1]};
        }
    }
    __syncthreads();        // X data fully consumed; safe to overwrite sA
    {
        float4 o0 = {vcur[0], vcur[1], vcur[2], vcur[3]};
        float4 o1 = {vcur[4], vcur[5], vcur[6], vcur[7]};
        *(float4*)(sA + L*SF + 4 + x0) = o0;
        *(float4*)(sA + L*SF + 8 + x0) = o1;
    }

    float wv[LQ*9];
    #pragma unroll
    for (int i = 0; i < LQ*9; ++i) wv[i] = wgt[i];
    __syncthreads();

    // ---- value iteration: v <- max_a (qr[a] + conv3x3(v, w[a])), packed f32 ----
    const int km1 = kptr[0] - 1;
    float* cur = sA;
    float* nxt = sB;
    for (int t = 0; t < km1; ++t) {
        // 3 window rows, 10 cols each -> 9 shifted f2 pairs per row (all-b128 loads)
        f2 pw[3][9];
        #pragma unroll
        for (int d = 0; d < 3; ++d) {
            float w10[10];
            load10(cur + (L-1+d)*SF + 4 + x0, w10);
            #pragma unroll
            for (int i = 0; i < 9; ++i) pw[d][i] = (f2){w10[i], w10[i+1]};
        }
        f2 vP[4];
        #pragma unroll
        for (int a = 0; a < LQ; ++a) {
            f2 acc0 = qr[a][0], acc1 = qr[a][1], acc2 = qr[a][2], acc3 = qr[a][3];
            #pragma unroll
            for (int d = 0; d < 3; ++d) {
                #pragma unroll
                for (int dx = 0; dx < 3; ++dx) {
                    float ww = wv[a*9 + d*3 + dx];
                    f2 wsv = {ww, ww};
                    acc0 = __builtin_elementwise_fma(pw[d][0+dx], wsv, acc0);
                    acc1 = __builtin_elementwise_fma(pw[d][2+dx], wsv, acc1);
                    acc2 = __builtin_elementwise_fma(pw[d][4+dx], wsv, acc2);
                    acc3 = __builtin_elementwise_fma(pw[d][6+dx], wsv, acc3);
                }
            }
            if (a == 0) { vP[0]=acc0; vP[1]=acc1; vP[2]=acc2; vP[3]=acc3; }
            else {
                vP[0] = __builtin_elementwise_max(vP[0], acc0);
                vP[1] = __builtin_elementwise_max(vP[1], acc1);
                vP[2] = __builtin_elementwise_max(vP[2], acc2);
                vP[3] = __builtin_elementwise_max(vP[3], acc3);
            }
        }
        float4 o0 = {vP[0].x, vP[0].y, vP[1].x, vP[1].y};
        float4 o1 = {vP[2].x, vP[2].y, vP[3].x, vP[3].y};
        *(float4*)(nxt + L*SF + 4 + x0) = o0;
        *(float4*)(nxt + L*SF + 8 + x0) = o1;
        __syncthreads();
        float* tmp = cur; cur = nxt; nxt = tmp;
    }

    // ---- write out owned row ----
    const float* vp = cur + L*SF + 4 + x0;
    float4 o0 = *(const float4*)(vp);
    float4 o1 = *(const float4*)(vp + 4);
    float* op = out + (size_t)b*HW*HW + (size_t)r*HW + x0;
    *(float4*)op = o0;
    *(float4*)(op + 4) = o1;
}

extern "C" void kernel_launch(void* const* d_in, const int* in_sizes, int n_in,
                              void* d_out, int out_size, void* d_ws, size_t ws_size,
                              hipStream_t stream) {
    const float* X   = (const float*)d_in[0];
    const float* h_w = (const float*)d_in[1];
    const float* h_b = (const float*)d_in[2];
    const float* r_w = (const float*)d_in[3];
    const float* q_w = (const float*)d_in[4];
    const float* w   = (const float*)d_in[5];
    const int*   k   = (const int*)d_in[6];
    float* out = (float*)d_out;
    float* ws  = (float*)d_ws;   // 19 floats

    vin_prep<<<1, 64, 0, stream>>>(h_w, h_b, r_w, ws);
    vin_main<<<128, 512, 0, stream>>>(X, q_w, w, k, ws, out);
}

// Round 8
// 158.146 us; speedup vs baseline: 3.6535x; 1.1180x over previous
//
#include <hip/hip_runtime.h>

typedef float f2 __attribute__((ext_vector_type(2)));

#define HW 64
#define XR (66*64)       // one staging region: 66 rows x 64 cols (rows 0,65 = zero pad)
#define LH 150
#define LQ 10

// weff[0..17] = sum_l r_w[l]*h_w[l][c][ky][kx], weff[18] = sum_l r_w[l]*h_b[l]
__global__ void vin_prep(const float* __restrict__ h_w,
                         const float* __restrict__ h_b,
                         const float* __restrict__ r_w,
                         float* __restrict__ weff) {
    int t = threadIdx.x;
    if (t < 18) {
        float s = 0.f;
        for (int l = 0; l < LH; ++l) s += r_w[l] * h_w[l*18 + t];
        weff[t] = s;
    } else if (t == 18) {
        float s = 0.f;
        for (int l = 0; l < LH; ++l) s += r_w[l] * h_b[l];
        weff[18] = s;
    }
}

// Full-wave lane shifts. wave_shr1 (0x138): lane i <- lane i-1 (lane 0 -> 0).
// wave_shl1 (0x130): lane i <- lane i+1 (lane 63 -> 0). bound_ctrl zero-fill
// == SAME padding at image columns 0 / 63 (lane == column).
__device__ __forceinline__ float dpp_wshr1(float x) {
    return __builtin_bit_cast(float, __builtin_amdgcn_update_dpp(
        0, __builtin_bit_cast(int, x), 0x138, 0xF, 0xF, true));
}
__device__ __forceinline__ float dpp_wshl1(float x) {
    return __builtin_bit_cast(float, __builtin_amdgcn_update_dpp(
        0, __builtin_bit_cast(int, x), 0x130, 0xF, 0xF, true));
}
__device__ __forceinline__ f2 dpp2_shr(f2 v) { return (f2){dpp_wshr1(v.x), dpp_wshr1(v.y)}; }
__device__ __forceinline__ f2 dpp2_shl(f2 v) { return (f2){dpp_wshl1(v.x), dpp_wshl1(v.y)}; }

// One block per image, 512 threads = 8 waves. lane l = column l; wave w owns
// rows 8w..8w+7 IN REGISTERS. Horizontal halos via wave DPP; vertical halos via
// 2 ds_write_b32 + 2 ds_read_b32 per lane per iter (parity slots, 1 barrier).
__global__ __launch_bounds__(512, 2)
void vin_main(const float* __restrict__ X,
              const float* __restrict__ q_w,
              const float* __restrict__ wgt,
              const int* __restrict__ kptr,
              const float* __restrict__ ws,
              float* __restrict__ out) {
    __shared__ float smem[3*XR];           // 50688 B: X0 | X1 | r (halo slots alias X0)
    float* sR = smem + 2*XR;
    // halo alias (valid after prologue): sHB[2][9][64] at smem+0 (bottom rows;
    // wave w writes [p][w+1], pad [p][0]=0), sHT[2][9][64] at smem+1152 (top rows;
    // wave w writes [p][w], pad [p][8]=0).
    float* sHB = smem;
    float* sHT = smem + 1152;

    const int b = blockIdx.x, tid = threadIdx.x;
    const int w = tid >> 6, l = tid & 63;

    for (int i = tid; i < 3*XR; i += 512) smem[i] = 0.f;
    __syncthreads();

    // ---- stage X (both channels), image rows 0..63 -> LDS rows 1..64 ----
    const float* Xb = X + (size_t)b * 2 * HW * HW;
    for (int i = tid; i < 2*64*16; i += 512) {
        int ch = i >> 10, j = i & 1023, row = j >> 4, c = j & 15;
        float4 v = *(const float4*)(Xb + ((size_t)ch*HW + row)*HW + c*4);
        *(float4*)(smem + ch*XR + (row+1)*64 + c*4) = v;
    }
    __syncthreads();

    // ---- r = conv3x3(X, weff) + beff, column mapping ----
    float wE[19];
    #pragma unroll
    for (int i = 0; i < 19; ++i) wE[i] = ws[i];
    float rloc[8];
    {
        float xc[2][10], xl[2][10], xr[2][10];
        #pragma unroll
        for (int ch = 0; ch < 2; ++ch)
            #pragma unroll
            for (int k = 0; k < 10; ++k) {
                xc[ch][k] = smem[ch*XR + (8*w + k)*64 + l];   // global row 8w-1+k
                xl[ch][k] = dpp_wshr1(xc[ch][k]);
                xr[ch][k] = dpp_wshl1(xc[ch][k]);
            }
        #pragma unroll
        for (int i = 0; i < 8; ++i) {
            float acc = wE[18];
            #pragma unroll
            for (int ch = 0; ch < 2; ++ch)
                #pragma unroll
                for (int dy = 0; dy < 3; ++dy) {
                    acc = fmaf(xl[ch][i+dy], wE[ch*9 + dy*3 + 0], acc);
                    acc = fmaf(xc[ch][i+dy], wE[ch*9 + dy*3 + 1], acc);
                    acc = fmaf(xr[ch][i+dy], wE[ch*9 + dy*3 + 2], acc);
                }
            rloc[i] = acc;
        }
    }
    #pragma unroll
    for (int i = 0; i < 8; ++i) sR[(8*w + i + 1)*64 + l] = rloc[i];
    __syncthreads();   // after this, X regions are dead -> halo slots may alias

    // ---- qr[a] = conv3x3(r, q_w[a]); v0 = max_a qr ----
    f2 qr[LQ][4];
    f2 vc[4];
    {
        float rc[10], rl[10], rr2[10];
        #pragma unroll
        for (int k = 0; k < 10; ++k) {
            rc[k]  = sR[(8*w + k)*64 + l];
            rl[k]  = dpp_wshr1(rc[k]);
            rr2[k] = dpp_wshl1(rc[k]);
        }
        float vcur[8];
        #pragma unroll
        for (int a = 0; a < LQ; ++a) {
            float qa[9];
            #pragma unroll
            for (int i = 0; i < 9; ++i) qa[i] = q_w[a*9 + i];
            float acc[8];
            #pragma unroll
            for (int i = 0; i < 8; ++i) {
                float s = 0.f;
                #pragma unroll
                for (int dy = 0; dy < 3; ++dy) {
                    s = fmaf(rl[i+dy],  qa[dy*3 + 0], s);
                    s = fmaf(rc[i+dy],  qa[dy*3 + 1], s);
                    s = fmaf(rr2[i+dy], qa[dy*3 + 2], s);
                }
                acc[i] = s;
                vcur[i] = a ? fmaxf(vcur[i], s) : s;
            }
            #pragma unroll
            for (int j = 0; j < 4; ++j) qr[a][j] = (f2){acc[2*j], acc[2*j+1]};
        }
        #pragma unroll
        for (int j = 0; j < 4; ++j) vc[j] = (f2){vcur[2*j], vcur[2*j+1]};
    }
    // zero the 4 halo pad rows (alias region; X dead since last barrier)
    if (tid < 256) {
        int p = tid >> 7, half = (tid >> 6) & 1, ll = tid & 63;
        if (half == 0) sHB[p*576 + 0*64 + ll] = 0.f;
        else           sHT[p*576 + 8*64 + ll] = 0.f;
    }

    float wv[LQ*9];
    #pragma unroll
    for (int i = 0; i < LQ*9; ++i) wv[i] = wgt[i];

    // ---- value iteration: v <- max_a (qr[a] + conv3x3(v, w[a])) ----
    const int km1 = kptr[0] - 1;
    const int wrB = (w+1)*64 + l;   // my bottom-row slot / partner's top-halo index
    const int wrT = w*64 + l;
    for (int t = 0; t < km1; ++t) {
        const int p = (t & 1) * 576;
        sHB[p + wrB] = vc[3].y;     // my row 8w+7
        sHT[p + wrT] = vc[0].x;     // my row 8w
        __syncthreads();
        float ht = sHB[p + wrT];    // row 8w-1 (zero for w==0)
        float hb = sHT[p + wrB];    // row 8w+8 (zero for w==7)

        // vv[0..9] = [ht, vcur0..7, hb]; aligned pairs P[j]=(vv2j,vv2j+1),
        // odd pairs O[j]=(vv2j+1,vv2j+2)=vc[j]
        f2 P[5];
        P[0] = (f2){ht,       vc[0].x};
        P[1] = (f2){vc[0].y,  vc[1].x};
        P[2] = (f2){vc[1].y,  vc[2].x};
        P[3] = (f2){vc[2].y,  vc[3].x};
        P[4] = (f2){vc[3].y,  hb};
        f2 PL[5], PR[5], OL[4], OR[4];
        #pragma unroll
        for (int j = 0; j < 5; ++j) { PL[j] = dpp2_shr(P[j]); PR[j] = dpp2_shl(P[j]); }
        #pragma unroll
        for (int j = 0; j < 4; ++j) { OL[j] = dpp2_shr(vc[j]); OR[j] = dpp2_shl(vc[j]); }

        f2 vn[4];
        #pragma unroll
        for (int a = 0; a < LQ; ++a) {
            f2 acc[4];
            #pragma unroll
            for (int j = 0; j < 4; ++j) acc[j] = qr[a][j];
            #pragma unroll
            for (int j = 0; j < 4; ++j) {
                // dy=0 -> P[j], dy=1 -> O[j], dy=2 -> P[j+1]; cols L/C/R
                float w00 = wv[a*9+0], w01 = wv[a*9+1], w02 = wv[a*9+2];
                float w10 = wv[a*9+3], w11 = wv[a*9+4], w12 = wv[a*9+5];
                float w20 = wv[a*9+6], w21 = wv[a*9+7], w22 = wv[a*9+8];
                acc[j] = __builtin_elementwise_fma(PL[j],   (f2){w00,w00}, acc[j]);
                acc[j] = __builtin_elementwise_fma(P[j],    (f2){w01,w01}, acc[j]);
                acc[j] = __builtin_elementwise_fma(PR[j],   (f2){w02,w02}, acc[j]);
                acc[j] = __builtin_elementwise_fma(OL[j],   (f2){w10,w10}, acc[j]);
                acc[j] = __builtin_elementwise_fma(vc[j],   (f2){w11,w11}, acc[j]);
                acc[j] = __builtin_elementwise_fma(OR[j],   (f2){w12,w12}, acc[j]);
                acc[j] = __builtin_elementwise_fma(PL[j+1], (f2){w20,w20}, acc[j]);
                acc[j] = __builtin_elementwise_fma(P[j+1],  (f2){w21,w21}, acc[j]);
                acc[j] = __builtin_elementwise_fma(PR[j+1], (f2){w22,w22}, acc[j]);
            }
            if (a == 0) { vn[0]=acc[0]; vn[1]=acc[1]; vn[2]=acc[2]; vn[3]=acc[3]; }
            else {
                vn[0] = __builtin_elementwise_max(vn[0], acc[0]);
                vn[1] = __builtin_elementwise_max(vn[1], acc[1]);
                vn[2] = __builtin_elementwise_max(vn[2], acc[2]);
                vn[3] = __builtin_elementwise_max(vn[3], acc[3]);
            }
        }
        vc[0] = vn[0]; vc[1] = vn[1]; vc[2] = vn[2]; vc[3] = vn[3];
    }

    // ---- write out: lane l -> column l, rows 8w..8w+7 (coalesced per wave) ----
    float* ob = out + (size_t)b*HW*HW + (size_t)(8*w)*HW + l;
    #pragma unroll
    for (int j = 0; j < 4; ++j) {
        ob[(2*j)*HW]   = vc[j].x;
        ob[(2*j+1)*HW] = vc[j].y;
    }
}

extern "C" void kernel_launch(void* const* d_in, const int* in_sizes, int n_in,
                              void* d_out, int out_size, void* d_ws, size_t ws_size,
                              hipStream_t stream) {
    const float* X   = (const float*)d_in[0];
    const float* h_w = (const float*)d_in[1];
    const float* h_b = (const float*)d_in[2];
    const float* r_w = (const float*)d_in[3];
    const float* q_w = (const float*)d_in[4];
    const float* w   = (const float*)d_in[5];
    const int*   k   = (const int*)d_in[6];
    float* out = (float*)d_out;
    float* ws  = (float*)d_ws;   // 19 floats

    vin_prep<<<1, 64, 0, stream>>>(h_w, h_b, r_w, ws);
    vin_main<<<128, 512, 0, stream>>>(X, q_w, w, k, ws, out);
}